// Round 1
// baseline (1895.058 us; speedup 1.0000x reference)
//
#include <hip/hip_runtime.h>

typedef short s8v __attribute__((ext_vector_type(8)));
typedef float f4v __attribute__((ext_vector_type(4)));
typedef unsigned short u16;

// ---------------- sizes ----------------
// V=50000 D=300 H=256 T=34 B=64 S=256; M = S*B = 16384; K_in padded 300->320
constexpr int MB = 64, SS = 256, DD = 300, DP = 320, HH = 256, G4 = 1024, TT = 34, TP = 48;
constexpr int MM = MB * SS; // 16384, row m = s*64 + b

// workspace offsets (bytes)
constexpr size_t OFF_XBF  = 0;                                   // [16384][320] bf16
constexpr size_t OFF_WIH  = OFF_XBF  + (size_t)MM * DP * 2;      // [2048][320] bf16
constexpr size_t OFF_WHH  = OFF_WIH  + (size_t)2048 * DP * 2;    // [2][1024][256] bf16
constexpr size_t OFF_WOUT = OFF_WHH  + (size_t)2048 * HH * 2;    // [48][512] bf16
constexpr size_t OFF_XG   = OFF_WOUT + (size_t)TP * 512 * 2;     // [16384][2048] bf16
constexpr size_t OFF_HBUF = OFF_XG   + (size_t)MM * 2048 * 2;    // [2buf][2dir][64][256] bf16
constexpr size_t OFF_HID  = OFF_HBUF + (size_t)4 * 64 * 256 * 2; // [16384][512] bf16
constexpr size_t OFF_EM   = OFF_HID  + (size_t)MM * 512 * 2;     // [16384][36] f32
constexpr size_t OFF_LLH  = OFF_EM   + (size_t)MM * 36 * 4;      // [64] f32
constexpr size_t OFF_SYNC = OFF_LLH  + 256;                      // [2][256] int

__device__ inline u16 f2bf(float f) {
  unsigned u = __builtin_bit_cast(unsigned, f);
  unsigned r = u + 0x7fffu + ((u >> 16) & 1u);
  return (u16)(r >> 16);
}
__device__ inline float bf2f(u16 h) {
  return __builtin_bit_cast(float, (unsigned)h << 16);
}
__device__ inline float sigf(float x) { return __fdividef(1.f, 1.f + __expf(-x)); }
__device__ inline float tanhf_(float x) {
  float e = __expf(2.f * x);
  return __fdividef(e - 1.f, e + 1.f);
}

// ---------------- K1: gather + bf16 conversions ----------------
constexpr int XBF_CH = MM * (DP / 8);       // 655360
constexpr int WIH_CH = 2048 * (DP / 8);     // 81920
constexpr int WHH_CH = 2048 * (HH / 8);     // 65536
constexpr int WOUT_CH = TP * (512 / 8);     // 3072
constexpr int TOT_CH = XBF_CH + WIH_CH + WHH_CH + WOUT_CH; // 805888

__global__ __launch_bounds__(256) void k_prep(
    const int* __restrict__ batch, const float* __restrict__ emb,
    const float* __restrict__ wihf, const float* __restrict__ wihb,
    const float* __restrict__ whhf, const float* __restrict__ whhb,
    const float* __restrict__ wout,
    u16* __restrict__ xbf, u16* __restrict__ wih,
    u16* __restrict__ whh, u16* __restrict__ wob) {
  int cid = blockIdx.x * 256 + threadIdx.x;
  if (cid >= TOT_CH) return;
  union { u16 u[8]; uint4 v; } pk;
  if (cid < XBF_CH) {
    int m = cid / 40, cc = cid - m * 40, d0 = cc * 8;
    int b = m & 63, s = m >> 6;
    int tok = batch[b * SS + s];
    const float* src = emb + (size_t)tok * DD;
    #pragma unroll
    for (int j = 0; j < 8; ++j) { int d = d0 + j; pk.u[j] = f2bf(d < DD ? src[d] : 0.f); }
    *(uint4*)(xbf + (size_t)m * DP + d0) = pk.v;
  } else if (cid < XBF_CH + WIH_CH) {
    int c2 = cid - XBF_CH;
    int row = c2 / 40, cc = c2 - row * 40, d0 = cc * 8;
    const float* src = row < 1024 ? (wihf + (size_t)row * DD) : (wihb + (size_t)(row - 1024) * DD);
    #pragma unroll
    for (int j = 0; j < 8; ++j) { int d = d0 + j; pk.u[j] = f2bf(d < DD ? src[d] : 0.f); }
    *(uint4*)(wih + (size_t)row * DP + d0) = pk.v;
  } else if (cid < XBF_CH + WIH_CH + WHH_CH) {
    int c2 = cid - (XBF_CH + WIH_CH);
    int row = c2 >> 5, d0 = (c2 & 31) * 8;
    const float* src = row < 1024 ? (whhf + (size_t)row * HH) : (whhb + (size_t)(row - 1024) * HH);
    #pragma unroll
    for (int j = 0; j < 8; ++j) pk.u[j] = f2bf(src[d0 + j]);
    *(uint4*)(whh + (size_t)row * HH + d0) = pk.v;
  } else {
    int c2 = cid - (XBF_CH + WIH_CH + WHH_CH);
    int row = c2 >> 6, d0 = (c2 & 63) * 8;
    #pragma unroll
    for (int j = 0; j < 8; ++j) pk.u[j] = f2bf(row < TT ? wout[(size_t)row * 512 + d0 + j] : 0.f);
    *(uint4*)(wob + (size_t)row * 512 + d0) = pk.v;
  }
}

// ---------------- K2: input-projection GEMM: xg[m][n] = xbf[m][k] . wih[n][k] + bias[n] ----------------
__global__ __launch_bounds__(256) void k_xg(
    const u16* __restrict__ xbf, const u16* __restrict__ wih,
    const float* __restrict__ bf_, const float* __restrict__ bb_,
    u16* __restrict__ xg) {
  __shared__ u16 As[128][40];
  __shared__ u16 Bs[128][40];
  int m0 = blockIdx.x * 128, n0 = blockIdx.y * 128;
  int tid = threadIdx.x, lane = tid & 63, wid = tid >> 6;
  int wr = wid >> 1, wc = wid & 1;
  int r_lo = lane & 15, kc = (lane >> 4) * 8, row_hi = (lane >> 4) * 4;
  f4v acc[4][4] = {};
  for (int kt = 0; kt < 10; ++kt) {
    int k0 = kt * 32;
    #pragma unroll
    for (int i = 0; i < 2; ++i) {
      int cid = tid + 256 * i;
      int row = cid >> 2, cc = cid & 3;
      *(uint4*)(&As[row][cc * 8]) = *(const uint4*)(xbf + (size_t)(m0 + row) * DP + k0 + cc * 8);
      *(uint4*)(&Bs[row][cc * 8]) = *(const uint4*)(wih + (size_t)(n0 + row) * DP + k0 + cc * 8);
    }
    __syncthreads();
    s8v af[4], bfr[4];
    #pragma unroll
    for (int mi = 0; mi < 4; ++mi) af[mi] = *(const s8v*)(&As[wr * 64 + mi * 16 + r_lo][kc]);
    #pragma unroll
    for (int ni = 0; ni < 4; ++ni) bfr[ni] = *(const s8v*)(&Bs[wc * 64 + ni * 16 + r_lo][kc]);
    #pragma unroll
    for (int mi = 0; mi < 4; ++mi)
      #pragma unroll
      for (int ni = 0; ni < 4; ++ni)
        acc[mi][ni] = __builtin_amdgcn_mfma_f32_16x16x32_bf16(af[mi], bfr[ni], acc[mi][ni], 0, 0, 0);
    __syncthreads();
  }
  #pragma unroll
  for (int mi = 0; mi < 4; ++mi)
    #pragma unroll
    for (int ni = 0; ni < 4; ++ni) {
      int n = n0 + wc * 64 + ni * 16 + r_lo;
      float bias = n < 1024 ? bf_[n] : bb_[n - 1024];
      #pragma unroll
      for (int r = 0; r < 4; ++r) {
        int m = m0 + wr * 64 + mi * 16 + row_hi + r;
        xg[(size_t)m * 2048 + n] = f2bf(acc[mi][ni][r] + bias);
      }
    }
}

// ---------------- K3: persistent bidirectional LSTM ----------------
// 16 wgs: dir = blk>>3, slice = blk&7 (32 h-units). Weights LDS-resident.
__global__ __launch_bounds__(256, 1) void k_lstm(
    const u16* __restrict__ xg, const u16* __restrict__ whh,
    u16* __restrict__ hbuf, u16* __restrict__ hidden, int* __restrict__ sync) {
  extern __shared__ char smem_raw[];
  u16* Wl = (u16*)smem_raw;          // [128][264]
  u16* hs = Wl + 128 * 264;          // [64][264]
  int dir = blockIdx.x >> 3, sl = blockIdx.x & 7, j0 = sl * 32;
  int tid = threadIdx.x, lane = tid & 63, wid = tid >> 6;
  int r_lo = lane & 15, kc = (lane >> 4) * 8, row_hi = (lane >> 4) * 4;
  int* cnt = sync + dir * 256;
  // load weight slice: local row = gate*32 + jl  ->  whh[dir][gate*256 + j0 + jl][:]
  #pragma unroll
  for (int i = 0; i < 16; ++i) {
    int cid = tid + 256 * i;
    int row = cid >> 5, cc = cid & 31;
    int gate = row >> 5, jl = row & 31;
    *(uint4*)(Wl + row * 264 + cc * 8) =
        *(const uint4*)(whh + (size_t)(dir * 1024 + gate * 256 + j0 + jl) * HH + cc * 8);
  }
  float cst[4][2] = {};
  for (int step = 0; step < 256; ++step) {
    int s = dir ? (255 - step) : step;
    int p = step & 1;
    const u16* hin = hbuf + (size_t)(p * 2 + dir) * 64 * 256;
    u16* hout = hbuf + (size_t)((p ^ 1) * 2 + dir) * 64 * 256;
    #pragma unroll
    for (int i = 0; i < 8; ++i) {
      int cid = tid + 256 * i;
      int row = cid >> 5, cc = cid & 31;
      *(uint4*)(hs + row * 264 + cc * 8) = *(const uint4*)(hin + row * 256 + cc * 8);
    }
    __syncthreads();
    f4v acc[8] = {};
    #pragma unroll
    for (int kt = 0; kt < 8; ++kt) {
      int k0 = kt * 32;
      s8v a = *(const s8v*)(hs + (wid * 16 + r_lo) * 264 + k0 + kc);
      #pragma unroll
      for (int nt = 0; nt < 8; ++nt) {
        s8v b = *(const s8v*)(Wl + (nt * 16 + r_lo) * 264 + k0 + kc);
        acc[nt] = __builtin_amdgcn_mfma_f32_16x16x32_bf16(a, b, acc[nt], 0, 0, 0);
      }
    }
    // epilogue: lane owns b = wid*16 + row_hi + r, jl = jj*16 + r_lo
    #pragma unroll
    for (int r = 0; r < 4; ++r) {
      int b = wid * 16 + row_hi + r;
      const u16* xb = xg + (size_t)(s * 64 + b) * 2048 + dir * 1024 + j0;
      #pragma unroll
      for (int jj = 0; jj < 2; ++jj) {
        int jl = jj * 16 + r_lo;
        float gi = acc[0 + jj][r] + bf2f(xb[0 * 256 + jl]);
        float gf = acc[2 + jj][r] + bf2f(xb[1 * 256 + jl]);
        float gg = acc[4 + jj][r] + bf2f(xb[2 * 256 + jl]);
        float go = acc[6 + jj][r] + bf2f(xb[3 * 256 + jl]);
        float cv = sigf(gf) * cst[r][jj] + sigf(gi) * tanhf_(gg);
        cst[r][jj] = cv;
        u16 hv = f2bf(sigf(go) * tanhf_(cv));
        hout[b * 256 + j0 + jl] = hv;
        hidden[(size_t)(s * 64 + b) * 512 + dir * 256 + j0 + jl] = hv;
      }
    }
    __syncthreads();
    if (tid == 0) {
      __hip_atomic_fetch_add(cnt + step, 1, __ATOMIC_ACQ_REL, __HIP_MEMORY_SCOPE_AGENT);
      while (__hip_atomic_load(cnt + step, __ATOMIC_ACQUIRE, __HIP_MEMORY_SCOPE_AGENT) < 8)
        __builtin_amdgcn_s_sleep(2);
    }
    __syncthreads();
  }
}

// ---------------- K4: emission GEMM: em[m][t] = hidden[m][k] . wout[t][k] + b_out[t] ----------------
__global__ __launch_bounds__(64) void k_emit(
    const u16* __restrict__ hidden, const u16* __restrict__ wob,
    const float* __restrict__ bout, float* __restrict__ em) {
  int m0 = blockIdx.x * 16;
  int lane = threadIdx.x;
  int r_lo = lane & 15, kc = (lane >> 4) * 8, row_hi = (lane >> 4) * 4;
  f4v acc[3] = {};
  #pragma unroll
  for (int kt = 0; kt < 16; ++kt) {
    int k0 = kt * 32 + kc;
    s8v a = *(const s8v*)(hidden + (size_t)(m0 + r_lo) * 512 + k0);
    #pragma unroll
    for (int nt = 0; nt < 3; ++nt) {
      s8v b = *(const s8v*)(wob + (size_t)(nt * 16 + r_lo) * 512 + k0);
      acc[nt] = __builtin_amdgcn_mfma_f32_16x16x32_bf16(a, b, acc[nt], 0, 0, 0);
    }
  }
  #pragma unroll
  for (int nt = 0; nt < 3; ++nt) {
    int t = nt * 16 + r_lo;
    if (t < TT) {
      float bo = bout[t];
      #pragma unroll
      for (int r = 0; r < 4; ++r)
        em[(size_t)(m0 + row_hi + r) * 36 + t] = acc[nt][r] + bo;
    }
  }
}

// ---------------- K5: CRF per-sequence NLL ----------------
__global__ __launch_bounds__(64) void k_crf(
    const float* __restrict__ em, const int* __restrict__ tags,
    const float* __restrict__ startt, const float* __restrict__ endt,
    const float* __restrict__ trans, float* __restrict__ llh) {
  __shared__ float tr[34][35];
  __shared__ float al[2][40];
  int b = blockIdx.x, l = threadIdx.x;
  for (int i = l; i < TT * TT; i += 64) tr[i / TT][i - (i / TT) * TT] = trans[i];
  const int* tg = tags + b * SS;
  float np = 0.f;
  for (int s = l; s < SS; s += 64) {
    int t = tg[s];
    np += em[(size_t)(s * 64 + b) * 36 + t];
    if (s < SS - 1) np += trans[t * TT + tg[s + 1]];
  }
  #pragma unroll
  for (int o = 32; o; o >>= 1) np += __shfl_down(np, o, 64);
  float num = 0.f;
  if (l == 0) num = np + startt[tg[0]] + endt[tg[SS - 1]];
  if (l < TT) al[0][l] = startt[l] + em[(size_t)(0 * 64 + b) * 36 + l];
  __syncthreads();
  for (int s = 1; s < SS; ++s) {
    int p = s & 1;
    if (l < TT) {
      float m = -1e30f;
      for (int t = 0; t < TT; ++t) m = fmaxf(m, al[p ^ 1][t] + tr[t][l]);
      float sum = 0.f;
      for (int t = 0; t < TT; ++t) sum += __expf(al[p ^ 1][t] + tr[t][l] - m);
      al[p][l] = m + __logf(sum) + em[(size_t)(s * 64 + b) * 36 + l];
    }
    __syncthreads();
  }
  if (l == 0) {
    int p = (SS - 1) & 1;
    float m = -1e30f;
    for (int t = 0; t < TT; ++t) m = fmaxf(m, al[p][t] + endt[t]);
    float sum = 0.f;
    for (int t = 0; t < TT; ++t) sum += __expf(al[p][t] + endt[t] - m);
    llh[b] = num - (m + __logf(sum));
  }
}

// ---------------- K6: final reduce ----------------
__global__ __launch_bounds__(64) void k_red(const float* __restrict__ llh, float* __restrict__ out) {
  float v = llh[threadIdx.x];
  #pragma unroll
  for (int o = 32; o; o >>= 1) v += __shfl_down(v, o, 64);
  if (threadIdx.x == 0) out[0] = -v * (1.f / 64.f);
}

extern "C" void kernel_launch(void* const* d_in, const int* in_sizes, int n_in,
                              void* d_out, int out_size, void* d_ws, size_t ws_size,
                              hipStream_t stream) {
  const int* batch = (const int*)d_in[0];
  const int* tags = (const int*)d_in[1];
  const float* emb = (const float*)d_in[3];
  const float* wihf = (const float*)d_in[4];
  const float* whhf = (const float*)d_in[5];
  const float* bf_ = (const float*)d_in[6];
  const float* wihb = (const float*)d_in[7];
  const float* whhb = (const float*)d_in[8];
  const float* bb_ = (const float*)d_in[9];
  const float* wout = (const float*)d_in[10];
  const float* bout = (const float*)d_in[11];
  const float* startt = (const float*)d_in[12];
  const float* endt = (const float*)d_in[13];
  const float* trans = (const float*)d_in[14];

  char* ws = (char*)d_ws;
  u16* xbf  = (u16*)(ws + OFF_XBF);
  u16* wih  = (u16*)(ws + OFF_WIH);
  u16* whh  = (u16*)(ws + OFF_WHH);
  u16* wob  = (u16*)(ws + OFF_WOUT);
  u16* xg   = (u16*)(ws + OFF_XG);
  u16* hbuf = (u16*)(ws + OFF_HBUF);
  u16* hid  = (u16*)(ws + OFF_HID);
  float* em = (float*)(ws + OFF_EM);
  float* llh = (float*)(ws + OFF_LLH);
  int* syncb = (int*)(ws + OFF_SYNC);
  float* out = (float*)d_out;

  hipFuncSetAttribute((const void*)k_lstm, hipFuncAttributeMaxDynamicSharedMemorySize, 192 * 264 * 2);

  hipMemsetAsync(hbuf, 0, 4 * 64 * 256 * 2, stream);
  hipMemsetAsync(syncb, 0, 2 * 256 * 4, stream);

  k_prep<<<TOT_CH / 256, 256, 0, stream>>>(batch, emb, wihf, wihb, whhf, whhb, wout,
                                           xbf, wih, whh, wob);
  k_xg<<<dim3(MM / 128, 2048 / 128), 256, 0, stream>>>(xbf, wih, bf_, bb_, xg);
  k_lstm<<<16, 256, 192 * 264 * 2, stream>>>(xg, whh, hbuf, hid, syncb);
  k_emit<<<MM / 16, 64, 0, stream>>>(hid, wob, bout, em);
  k_crf<<<64, 64, 0, stream>>>(em, tags, startt, endt, trans, llh);
  k_red<<<1, 64, 0, stream>>>(llh, out);
}